// Round 2
// baseline (15625.124 us; speedup 1.0000x reference)
//
#include <hip/hip_runtime.h>
#include <hip/hip_bf16.h>

// Problem constants
#define B_   64
#define S_   800
#define DIN_ 64
#define D_   512
#define H_   8
#define DH_  64
#define M_   64
#define L_   2
#define FF_  2048

__device__ __forceinline__ unsigned flipf(float f){
  unsigned u = __float_as_uint(f);
  return u ^ (((unsigned)((int)u >> 31)) | 0x80000000u);
}
__device__ __forceinline__ float unflipf(unsigned u){
  unsigned b = (u & 0x80000000u) ? (u ^ 0x80000000u) : ~u;
  return __uint_as_float(b);
}
__device__ __forceinline__ float gelu_f(float x){
  float x3 = x*x*x;
  return 0.5f*x*(1.f + tanhf(0.7978845608028654f*(x + 0.044715f*x3)));
}

// ---------------- Generic fp32 SGEMM: C[r,n] = act(A@Bw + bias) (+res) -----
// 128x128 tile, BK=8, 256 threads, 8x8 per thread. Row-guarded (any row count).
// RES: res row index = res_mod ? (r % res_mod) : r   (embed uses pos with mod S)
template<int ACT, int RES>
__global__ __launch_bounds__(256)
void gemm_k(const float* __restrict__ A, const float* __restrict__ Bw,
            const float* __restrict__ bias, const float* __restrict__ res,
            float* __restrict__ C, int rows, int N, int K, int res_mod)
{
  __shared__ float As[8][128];
  __shared__ float Bs[8][128];
  const int tid  = threadIdx.x;
  const int row0 = blockIdx.y*128, col0 = blockIdx.x*128;
  const int ty = tid>>4,  tx = tid&15;
  const int arow = tid>>1, ac4 = (tid&1)*4;
  const int brow = tid>>5, bc4 = (tid&31)*4;
  const int ar = min(row0 + arow, rows-1);        // clamped (duplicate) load
  const float* Ap = A + (size_t)ar*K + ac4;
  const float* Bp = Bw + (size_t)brow*N + col0 + bc4;
  float acc[8][8];
  #pragma unroll
  for (int i=0;i<8;i++)
    #pragma unroll
    for (int j=0;j<8;j++) acc[i][j]=0.f;

  for (int k0=0;k0<K;k0+=8){
    float4 av = *(const float4*)(Ap + k0);
    float4 bv = *(const float4*)(Bp + (size_t)k0*N);
    As[ac4+0][arow]=av.x; As[ac4+1][arow]=av.y;
    As[ac4+2][arow]=av.z; As[ac4+3][arow]=av.w;
    *(float4*)(&Bs[brow][bc4]) = bv;
    __syncthreads();
    #pragma unroll
    for (int kk=0;kk<8;++kk){
      float4 a0 = *(const float4*)(&As[kk][ty*8]);
      float4 a1 = *(const float4*)(&As[kk][ty*8+4]);
      float4 b0 = *(const float4*)(&Bs[kk][tx*8]);
      float4 b1 = *(const float4*)(&Bs[kk][tx*8+4]);
      float a[8]={a0.x,a0.y,a0.z,a0.w,a1.x,a1.y,a1.z,a1.w};
      float b[8]={b0.x,b0.y,b0.z,b0.w,b1.x,b1.y,b1.z,b1.w};
      #pragma unroll
      for (int i=0;i<8;i++)
        #pragma unroll
        for (int j=0;j<8;j++) acc[i][j] += a[i]*b[j];
    }
    __syncthreads();
  }
  #pragma unroll
  for (int i=0;i<8;i++){
    const int r = row0 + ty*8 + i;
    if (r >= rows) continue;
    #pragma unroll
    for (int j=0;j<8;j++){
      const int n = col0 + tx*8 + j;
      float v = acc[i][j] + bias[n];
      if (ACT) v = gelu_f(v);
      if (RES) v += res[(size_t)(res_mod ? (r % res_mod) : r)*N + n];
      C[(size_t)r*N + n] = v;
    }
  }
}

// ---------------- LayerNorm: one wave per row of 512 ----------------------
__global__ __launch_bounds__(256)
void ln_k(const float* __restrict__ x, const float* __restrict__ g,
          const float* __restrict__ b, float* __restrict__ y)
{
  const int wid = threadIdx.x>>6, lane = threadIdx.x&63;
  const size_t row = (size_t)blockIdx.x*4 + wid;
  const float* xr = x + row*D_;
  float4 v0 = *(const float4*)(xr + lane*4);
  float4 v1 = *(const float4*)(xr + 256 + lane*4);
  float s  = v0.x+v0.y+v0.z+v0.w + v1.x+v1.y+v1.z+v1.w;
  float ss = v0.x*v0.x+v0.y*v0.y+v0.z*v0.z+v0.w*v0.w
           + v1.x*v1.x+v1.y*v1.y+v1.z*v1.z+v1.w*v1.w;
  #pragma unroll
  for (int o=32;o;o>>=1){ s += __shfl_xor(s,o); ss += __shfl_xor(ss,o); }
  const float mean = s*(1.f/D_);
  const float rstd = rsqrtf(ss*(1.f/D_) - mean*mean + 1e-5f);
  float4 g0 = *(const float4*)(g + lane*4);
  float4 g1 = *(const float4*)(g + 256 + lane*4);
  float4 b0 = *(const float4*)(b + lane*4);
  float4 b1 = *(const float4*)(b + 256 + lane*4);
  float4 o0, o1;
  o0.x=(v0.x-mean)*rstd*g0.x+b0.x; o0.y=(v0.y-mean)*rstd*g0.y+b0.y;
  o0.z=(v0.z-mean)*rstd*g0.z+b0.z; o0.w=(v0.w-mean)*rstd*g0.w+b0.w;
  o1.x=(v1.x-mean)*rstd*g1.x+b1.x; o1.y=(v1.y-mean)*rstd*g1.y+b1.y;
  o1.z=(v1.z-mean)*rstd*g1.z+b1.z; o1.w=(v1.w-mean)*rstd*g1.w+b1.w;
  float* yr = y + row*D_;
  *(float4*)(yr + lane*4) = o0;
  *(float4*)(yr + 256 + lane*4) = o1;
}

// ---------------- kmax init ------------------------------------------------
__global__ void kinit_k(unsigned* __restrict__ kmax, int n){
  int i = blockIdx.x*256 + threadIdx.x;
  if (i < n) kmax[i] = 0u;   // flipped-float identity (< any finite value)
}

// ---------------- FAVOR+ feature map ---------------------------------------
// src in chunk-local [NB,S,H,DH]; dst in chunk-local [NB,H,S,M].
// QUERY=1: full qp = ratio*(exp(dd - diag - rowmax)+eps)
// QUERY=0: dst = dd - diag, atomicMax per-(b,h) of rowmax(dd) (flipped uint)
template<int QUERY>
__global__ __launch_bounds__(256)
void feat_k(const float* __restrict__ src, const float* __restrict__ proj,
            float* __restrict__ dst, unsigned* __restrict__ kmax, int nbh)
{
  __shared__ float pT[64*64];   // pT[d*64+m] = proj[m*64+d]
  const int tid = threadIdx.x;
  for (int i=tid;i<4096;i+=256) pT[(i&63)*64 + (i>>6)] = proj[i];
  __syncthreads();
  const int wid = tid>>6, lane = tid&63;
  const float NORM = 0.35355339059327373f;  // 1/64^{1/4}
  const int total = nbh*S_;
  for (int r = blockIdx.x*4 + wid; r < total; r += gridDim.x*4){
    const int bh = r / S_, s = r - bh*S_;
    const int b = bh >> 3, h = bh & 7;
    float dn = src[((size_t)(b*S_+s)*H_ + h)*64 + lane] * NORM;
    float sq = dn*dn;
    #pragma unroll
    for (int o=32;o;o>>=1) sq += __shfl_xor(sq,o);
    const float diag = 0.5f*sq;
    float acc = 0.f;
    #pragma unroll
    for (int d=0;d<64;++d) acc += __shfl(dn,d) * pT[d*64 + lane];
    float mx = acc;
    #pragma unroll
    for (int o=32;o;o>>=1) mx = fmaxf(mx, __shfl_xor(mx,o));
    if (QUERY){
      dst[(size_t)r*64 + lane] = 0.125f*(expf(acc - diag - mx) + 1e-4f);
    } else {
      dst[(size_t)r*64 + lane] = acc - diag;
      if (lane==0) atomicMax(&kmax[bh], flipf(mx));
    }
  }
}

// ---------------- kp finalize: exp with global stab, plus kps = sum_s kp ---
__global__ __launch_bounds__(256)
void kpfin_k(float* __restrict__ kp, const unsigned* __restrict__ kmax,
             float* __restrict__ kps)
{
  __shared__ float red[256][4];
  const int bh = blockIdx.x, tid = threadIdx.x;
  const float stab = unflipf(kmax[bh]);
  float* base = kp + (size_t)bh*S_*64;
  float p0=0,p1=0,p2=0,p3=0;
  for (int i=tid; i < S_*16; i += 256){
    float4 vv = *(float4*)(base + (size_t)i*4);
    vv.x = 0.125f*(expf(vv.x - stab)+1e-4f);
    vv.y = 0.125f*(expf(vv.y - stab)+1e-4f);
    vv.z = 0.125f*(expf(vv.z - stab)+1e-4f);
    vv.w = 0.125f*(expf(vv.w - stab)+1e-4f);
    *(float4*)(base + (size_t)i*4) = vv;
    p0+=vv.x; p1+=vv.y; p2+=vv.z; p3+=vv.w;
  }
  red[tid][0]=p0; red[tid][1]=p1; red[tid][2]=p2; red[tid][3]=p3;
  __syncthreads();
  if (tid < 64){
    const int g = tid>>2, c = tid&3;
    float s = 0.f;
    #pragma unroll
    for (int j=0;j<16;j++) s += red[g + j*16][c];
    kps[bh*64 + tid] = s;
  }
}

// ---------------- ctx[bh,m,d] = sum_s kp[bh,s,m]*v[b,s,h,d] ---------------
__global__ __launch_bounds__(256)
void ctx_k(const float* __restrict__ kp, const float* __restrict__ v,
           float* __restrict__ ctx)
{
  __shared__ float kc[32][64], vc[32][64];
  const int bh = blockIdx.x, tid = threadIdx.x;
  const int b = bh>>3, h = bh&7;
  const float* kpb = kp + (size_t)bh*S_*64;
  const int mq = tid>>4, dq = tid&15;
  float acc[4][4];
  #pragma unroll
  for (int i=0;i<4;i++)
    #pragma unroll
    for (int j=0;j<4;j++) acc[i][j]=0.f;
  for (int s0=0; s0<S_; s0+=32){
    for (int i=tid; i<512; i+=256){
      const int rr = i>>4, cc = (i&15)*4;
      *(float4*)&kc[rr][cc] = *(const float4*)(kpb + (size_t)(s0+rr)*64 + cc);
      *(float4*)&vc[rr][cc] = *(const float4*)(v + ((size_t)(b*S_+s0+rr)*H_ + h)*64 + cc);
    }
    __syncthreads();
    #pragma unroll 8
    for (int ssi=0; ssi<32; ++ssi){
      float a0=kc[ssi][mq*4+0],a1=kc[ssi][mq*4+1],a2=kc[ssi][mq*4+2],a3=kc[ssi][mq*4+3];
      float b0=vc[ssi][dq*4+0],b1=vc[ssi][dq*4+1],b2=vc[ssi][dq*4+2],b3=vc[ssi][dq*4+3];
      acc[0][0]+=a0*b0; acc[0][1]+=a0*b1; acc[0][2]+=a0*b2; acc[0][3]+=a0*b3;
      acc[1][0]+=a1*b0; acc[1][1]+=a1*b1; acc[1][2]+=a1*b2; acc[1][3]+=a1*b3;
      acc[2][0]+=a2*b0; acc[2][1]+=a2*b1; acc[2][2]+=a2*b2; acc[2][3]+=a2*b3;
      acc[3][0]+=a3*b0; acc[3][1]+=a3*b1; acc[3][2]+=a3*b2; acc[3][3]+=a3*b3;
    }
    __syncthreads();
  }
  #pragma unroll
  for (int i=0;i<4;i++)
    #pragma unroll
    for (int j=0;j<4;j++)
      ctx[((size_t)bh*64 + mq*4+i)*64 + dq*4+j] = acc[i][j];
}

// ---------------- out[b,s,h,d] = (qp[bh,s,:]@ctx[bh,:,d]) / den -----------
__global__ __launch_bounds__(256)
void attnout_k(const float* __restrict__ qp, const float* __restrict__ ctx,
               const float* __restrict__ kps, float* __restrict__ out)
{
  __shared__ float cl[4096];
  __shared__ float kl[64];
  const int bh = blockIdx.x, tid = threadIdx.x;
  for (int i=tid;i<4096;i+=256) cl[i] = ctx[(size_t)bh*4096 + i];
  if (tid<64) kl[tid] = kps[bh*64+tid];
  __syncthreads();
  const int wid = tid>>6, lane = tid&63;
  const int b = bh>>3, h = bh&7;
  const int send = min((int)(blockIdx.y*64+64), S_);
  for (int s = blockIdx.y*64 + wid; s < send; s += 4){
    float qreg = qp[((size_t)bh*S_ + s)*64 + lane];
    float den = qreg * kl[lane];
    #pragma unroll
    for (int o=32;o;o>>=1) den += __shfl_xor(den,o);
    float acc = 0.f;
    #pragma unroll
    for (int m=0;m<64;++m) acc += __shfl(qreg,m)*cl[m*64+lane];
    out[((size_t)(b*S_+s)*H_ + h)*64 + lane] = acc / den;
  }
}

// ---------------- head: out[b,c] = (mean_s h[b,s,:]) @ fc_w + fc_b ---------
__global__ __launch_bounds__(256)
void head_k(const float* __restrict__ h, const float* __restrict__ fcw,
            const float* __restrict__ fcb, float* __restrict__ out)
{
  __shared__ float red[256][2];
  const int b = blockIdx.x, tid = threadIdx.x;
  const float* hb = h + (size_t)b*S_*D_;
  float s0=0.f, s1=0.f;
  for (int s=0; s<S_; ++s){
    s0 += hb[(size_t)s*D_ + tid];
    s1 += hb[(size_t)s*D_ + tid + 256];
  }
  const float m0 = s0*(1.f/S_), m1 = s1*(1.f/S_);
  red[tid][0] = m0*fcw[tid*2+0] + m1*fcw[(tid+256)*2+0];
  red[tid][1] = m0*fcw[tid*2+1] + m1*fcw[(tid+256)*2+1];
  __syncthreads();
  for (int st=128; st; st>>=1){
    if (tid<st){ red[tid][0]+=red[tid+st][0]; red[tid][1]+=red[tid+st][1]; }
    __syncthreads();
  }
  if (tid==0){ out[b*2+0]=red[0][0]+fcb[0]; out[b*2+1]=red[0][1]+fcb[1]; }
}

extern "C" void kernel_launch(void* const* d_in, const int* in_sizes, int n_in,
                              void* d_out, int out_size, void* d_ws, size_t ws_size,
                              hipStream_t stream)
{
  const float* x     = (const float*)d_in[0];
  const float* emb_w = (const float*)d_in[1];
  const float* emb_b = (const float*)d_in[2];
  const float* pos   = (const float*)d_in[3];
  const float* ln1_g = (const float*)d_in[4];
  const float* ln1_b = (const float*)d_in[5];
  const float* wq    = (const float*)d_in[6];
  const float* bq    = (const float*)d_in[7];
  const float* wk    = (const float*)d_in[8];
  const float* bk    = (const float*)d_in[9];
  const float* wv    = (const float*)d_in[10];
  const float* bv    = (const float*)d_in[11];
  const float* wo    = (const float*)d_in[12];
  const float* bo    = (const float*)d_in[13];
  const float* proj  = (const float*)d_in[14];
  const float* ln2_g = (const float*)d_in[15];
  const float* ln2_b = (const float*)d_in[16];
  const float* w1    = (const float*)d_in[17];
  const float* b1    = (const float*)d_in[18];
  const float* w2    = (const float*)d_in[19];
  const float* b2    = (const float*)d_in[20];
  const float* fc_w  = (const float*)d_in[21];
  const float* fc_b  = (const float*)d_in[22];
  float* out = (float*)d_out;

  // Pick largest batch-chunk NB (divisor of 64) whose scratch fits ws_size.
  int NB = 64;
  size_t RC = 0, need = 0;
  for (;; NB >>= 1){
    RC = (size_t)NB * S_;
    size_t nbh = (size_t)NB * H_;
    need = (5*RC*D_ + nbh*4096 + nbh*64)*4 + nbh*4;
    if (need <= ws_size || NB == 1) break;
  }
  if (need > ws_size) return;  // < ~9 MB scratch: cannot run

  float* ws  = (float*)d_ws;
  float* hc  = ws;            // chunk residual stream [RC, D]
  float* B1  = ws + RC*D_;    // y / qp / ln2-out
  float* B2  = ws + 2*RC*D_;  // q / kp / ffn-hidden sub-chunk
  float* B3  = ws + 3*RC*D_;  // k / attn-out
  float* B4  = ws + 4*RC*D_;  // v
  float* ctx = ws + 5*RC*D_;                      // nbh*64*64
  const int NBH = NB * H_;
  float* kps = ctx + (size_t)NBH*4096;            // nbh*64
  unsigned* kmax = (unsigned*)(kps + NBH*64);     // nbh

  dim3 blk(256);
  const int rows = (int)RC;
  const int rgrid = (rows + 127)/128;
  const int frows = (rows/4 < 2048) ? rows/4 : 2048;
  const int CHR = rows/4;                         // FFN sub-chunk rows
  const int cgrid = (CHR + 127)/128;

  for (int bc = 0; bc < B_/NB; ++bc){
    const float* xc = x + (size_t)bc*RC*DIN_;
    float* outc = out + (size_t)bc*NB*2;

    // h = x @ emb_w + emb_b + pos[s]
    gemm_k<0,1><<<dim3(D_/128, rgrid), blk, 0, stream>>>(
        xc, emb_w, emb_b, pos, hc, rows, D_, DIN_, S_);

    for (int l=0; l<L_; ++l){
      const float* wql = wq + (size_t)l*D_*D_;  const float* bql = bq + (size_t)l*D_;
      const float* wkl = wk + (size_t)l*D_*D_;  const float* bkl = bk + (size_t)l*D_;
      const float* wvl = wv + (size_t)l*D_*D_;  const float* bvl = bv + (size_t)l*D_;
      const float* wol = wo + (size_t)l*D_*D_;  const float* bol = bo + (size_t)l*D_;
      const float* pjl = proj + (size_t)l*M_*DH_;
      const float* w1l = w1 + (size_t)l*D_*FF_; const float* b1l = b1 + (size_t)l*FF_;
      const float* w2l = w2 + (size_t)l*FF_*D_; const float* b2l = b2 + (size_t)l*D_;

      // y = LN(h)
      ln_k<<<rows/4, blk, 0, stream>>>(hc, ln1_g + (size_t)l*D_, ln1_b + (size_t)l*D_, B1);
      // q,k,v (chunk-local [NB,S,H,DH] layout)
      gemm_k<0,0><<<dim3(4, rgrid), blk, 0, stream>>>(B1, wql, bql, nullptr, B2, rows, D_, D_, 0);
      gemm_k<0,0><<<dim3(4, rgrid), blk, 0, stream>>>(B1, wkl, bkl, nullptr, B3, rows, D_, D_, 0);
      gemm_k<0,0><<<dim3(4, rgrid), blk, 0, stream>>>(B1, wvl, bvl, nullptr, B4, rows, D_, D_, 0);
      // qp (B2 -> B1), kp pass1 (B3 -> B2) + stab, finalize + kps
      feat_k<1><<<frows, blk, 0, stream>>>(B2, pjl, B1, nullptr, NBH);
      kinit_k<<<(NBH+255)/256, blk, 0, stream>>>(kmax, NBH);
      feat_k<0><<<frows, blk, 0, stream>>>(B3, pjl, B2, kmax, NBH);
      kpfin_k<<<NBH, blk, 0, stream>>>(B2, kmax, kps);
      // ctx = kp^T @ v ; out = (qp@ctx)*d_inv  -> B3 chunk-local [NB,S,D]
      ctx_k<<<NBH, blk, 0, stream>>>(B2, B4, ctx);
      attnout_k<<<dim3(NBH, (S_+63)/64), blk, 0, stream>>>(B1, ctx, kps, B3);
      // h += out @ wo + bo
      gemm_k<0,1><<<dim3(4, rgrid), blk, 0, stream>>>(B3, wol, bol, hc, hc, rows, D_, D_, 0);
      // y = LN2(h); FFN in 4 row sub-chunks: h += gelu(y@w1+b1)@w2 + b2
      ln_k<<<rows/4, blk, 0, stream>>>(hc, ln2_g + (size_t)l*D_, ln2_b + (size_t)l*D_, B1);
      for (int c=0;c<4;++c){
        float* yc = B1 + (size_t)c*CHR*D_;
        float* hcc = hc + (size_t)c*CHR*D_;
        gemm_k<1,0><<<dim3(FF_/128, cgrid), blk, 0, stream>>>(yc, w1l, b1l, nullptr, B2, CHR, FF_, D_, 0);
        gemm_k<0,1><<<dim3(D_/128, cgrid), blk, 0, stream>>>(B2, w2l, b2l, hcc, hcc, CHR, D_, FF_, 0);
      }
    }
    head_k<<<NB, blk, 0, stream>>>(hc, fc_w, fc_b, outc);
  }
}

// Round 3
// 8002.785 us; speedup vs baseline: 1.9525x; 1.9525x over previous
//
#include <hip/hip_runtime.h>
#include <hip/hip_bf16.h>

// Problem constants
#define B_   64
#define S_   800
#define DIN_ 64
#define D_   512
#define H_   8
#define DH_  64
#define M_   64
#define L_   2
#define FF_  2048

typedef __hip_bfloat16 bf16;
typedef __attribute__((ext_vector_type(8))) short bf16x8;
typedef __attribute__((ext_vector_type(4))) float f32x4;

#define NORM_ 0.35355339059327373f   // 64^(-1/4)

__device__ __forceinline__ unsigned flipf(float f){
  unsigned u = __float_as_uint(f);
  return u ^ (((unsigned)((int)u >> 31)) | 0x80000000u);
}
__device__ __forceinline__ float unflipf(unsigned u){
  unsigned b = (u & 0x80000000u) ? (u ^ 0x80000000u) : ~u;
  return __uint_as_float(b);
}
__device__ __forceinline__ float gelu_f(float x){
  float x3 = x*x*x;
  return 0.5f*x*(1.f + tanhf(0.7978845608028654f*(x + 0.044715f*x3)));
}
__device__ __forceinline__ void st_bf4(bf16* p, float4 v){
  union { bf16 b[4]; unsigned long long u; } q;
  q.b[0]=__float2bfloat16(v.x); q.b[1]=__float2bfloat16(v.y);
  q.b[2]=__float2bfloat16(v.z); q.b[3]=__float2bfloat16(v.w);
  *(unsigned long long*)p = q.u;
}

// ---------------- bf16 MFMA GEMM ------------------------------------------
// C[r,n] = act(A@W + bias) (+res).  A bf16 [rows][K], Wt bf16 [N][K] (pre-T).
// BM=BN=128, BK=32, 256 thr = 4 waves (2x2 of 64x64), 16x16x32 MFMA.
// OUTB: 0 -> fp32 store to Cf; 1 -> bf16 store to Cb.
template<int ACT, int RES, int OUTB>
__global__ __launch_bounds__(256)
void gemm_bf(const bf16* __restrict__ A, const bf16* __restrict__ Wt,
             const float* __restrict__ bias, const float* __restrict__ res,
             float* __restrict__ Cf, bf16* __restrict__ Cb,
             int rows, int N, int K, int res_mod)
{
  __shared__ bf16 As[128][40];   // 80B rows: conflict-minimal for b128 r/w
  __shared__ bf16 Bs[128][40];
  const int tid = threadIdx.x;
  const int wave = tid>>6, lane = tid&63;
  const int row0 = blockIdx.y*128, col0 = blockIdx.x*128;
  const int wm = (wave>>1)*64, wn = (wave&1)*64;
  const int sr = tid>>1, sk = (tid&1)*16;
  const int arow = min(row0+sr, rows-1);
  const bf16* Ap = A  + (size_t)arow*K + sk;
  const bf16* Bp = Wt + (size_t)(col0+sr)*K + sk;
  const int lr = lane&15, lk = (lane>>4)*8;
  f32x4 acc[4][4];
  #pragma unroll
  for (int i=0;i<4;i++)
    #pragma unroll
    for (int j=0;j<4;j++) acc[i][j] = (f32x4){0.f,0.f,0.f,0.f};

  for (int k0=0; k0<K; k0+=32){
    bf16x8 av0 = *(const bf16x8*)(Ap + k0);
    bf16x8 av1 = *(const bf16x8*)(Ap + k0 + 8);
    bf16x8 bv0 = *(const bf16x8*)(Bp + k0);
    bf16x8 bv1 = *(const bf16x8*)(Bp + k0 + 8);
    __syncthreads();
    *(bf16x8*)&As[sr][sk]   = av0;  *(bf16x8*)&As[sr][sk+8] = av1;
    *(bf16x8*)&Bs[sr][sk]   = bv0;  *(bf16x8*)&Bs[sr][sk+8] = bv1;
    __syncthreads();
    bf16x8 af[4], bfv[4];
    #pragma unroll
    for (int mi=0;mi<4;mi++) af[mi]  = *(const bf16x8*)&As[wm + mi*16 + lr][lk];
    #pragma unroll
    for (int ni=0;ni<4;ni++) bfv[ni] = *(const bf16x8*)&Bs[wn + ni*16 + lr][lk];
    #pragma unroll
    for (int mi=0;mi<4;mi++)
      #pragma unroll
      for (int ni=0;ni<4;ni++)
        acc[mi][ni] = __builtin_amdgcn_mfma_f32_16x16x32_bf16(af[mi], bfv[ni], acc[mi][ni], 0,0,0);
  }
  // epilogue: C row = (lane>>4)*4 + i, col = lane&15  [m89/m91 layout]
  #pragma unroll
  for (int mi=0;mi<4;mi++){
    #pragma unroll
    for (int i=0;i<4;i++){
      const int r = row0 + wm + mi*16 + (lane>>4)*4 + i;
      if (r >= rows) continue;
      #pragma unroll
      for (int ni=0;ni<4;ni++){
        const int c = col0 + wn + ni*16 + lr;
        float v = acc[mi][ni][i] + bias[c];
        if (ACT) v = gelu_f(v);
        if (RES) v += res[(size_t)(res_mod ? (r % res_mod) : r)*N + c];
        if (OUTB) Cb[(size_t)r*N + c] = __float2bfloat16(v);
        else      Cf[(size_t)r*N + c] = v;
      }
    }
  }
}

// ---------------- weight transpose+convert: src f32 [K][N] -> dst bf16 [N][K]
__global__ __launch_bounds__(256)
void convT_k(const float* __restrict__ src, bf16* __restrict__ dst, int K, int N)
{
  __shared__ float t[32][33];
  const int n0 = blockIdx.x*32, k0 = blockIdx.y*32;
  const int j = threadIdx.x&31, i0 = threadIdx.x>>5;
  #pragma unroll
  for (int i=i0; i<32; i+=8) t[i][j] = src[(size_t)(k0+i)*N + n0 + j];
  __syncthreads();
  #pragma unroll
  for (int i=i0; i<32; i+=8) dst[(size_t)(n0+i)*K + k0 + j] = __float2bfloat16(t[j][i]);
}

// ---------------- elementwise f32 -> bf16 ---------------------------------
__global__ void conv_k(const float* __restrict__ src, bf16* __restrict__ dst, int n4)
{
  int i = blockIdx.x*256 + threadIdx.x;
  if (i < n4){
    float4 v = ((const float4*)src)[i];
    st_bf4(dst + (size_t)i*4, v);
  }
}

// ---------------- folded feature weight: WpT[h*64+m][c] = norm*sum_d w[c,h*64+d]*proj[m,d]
__global__ __launch_bounds__(256)
void projw_k(const float* __restrict__ w, const float* __restrict__ proj,
             bf16* __restrict__ wpT)
{
  __shared__ float pj[64][64];   // [m][d] (broadcast reads)
  __shared__ float wsh[64][65];  // [c][d]
  const int h = blockIdx.x, c0 = blockIdx.y*64;
  const int tid = threadIdx.x, lane = tid&63, tg = tid>>6;
  for (int i=tid; i<4096; i+=256) pj[i>>6][i&63] = proj[i];
  for (int i=tg; i<64; i+=4) wsh[i][lane] = w[(size_t)(c0+i)*512 + h*64 + lane];
  __syncthreads();
  float acc[16];
  #pragma unroll
  for (int j=0;j<16;j++) acc[j]=0.f;
  for (int d=0; d<64; ++d){
    float wv = wsh[lane][d];
    #pragma unroll
    for (int j=0;j<16;j++) acc[j] += wv * pj[tg*16+j][d];
  }
  #pragma unroll
  for (int j=0;j<16;j++)
    wpT[(size_t)(h*64 + tg*16 + j)*512 + c0 + lane] = __float2bfloat16(acc[j]*NORM_);
}

// ---------------- folded feature bias: bqp[h*64+m] = norm*sum_d b[h*64+d]*proj[m,d]
__global__ void bproj_k(const float* __restrict__ b, const float* __restrict__ proj,
                        float* __restrict__ bp)
{
  int hm = blockIdx.x*256 + threadIdx.x;
  if (hm >= 512) return;
  int h = hm>>6, m = hm&63;
  float acc = 0.f;
  for (int d=0; d<64; ++d) acc += b[h*64+d]*proj[m*64+d];
  bp[hm] = acc*NORM_;
}

// ---------------- LayerNorm: one wave per row of 512, bf16 out -------------
__global__ __launch_bounds__(256)
void ln_k(const float* __restrict__ x, const float* __restrict__ g,
          const float* __restrict__ b, bf16* __restrict__ y)
{
  const int wid = threadIdx.x>>6, lane = threadIdx.x&63;
  const size_t row = (size_t)blockIdx.x*4 + wid;
  const float* xr = x + row*D_;
  float4 v0 = *(const float4*)(xr + lane*4);
  float4 v1 = *(const float4*)(xr + 256 + lane*4);
  float s  = v0.x+v0.y+v0.z+v0.w + v1.x+v1.y+v1.z+v1.w;
  float ss = v0.x*v0.x+v0.y*v0.y+v0.z*v0.z+v0.w*v0.w
           + v1.x*v1.x+v1.y*v1.y+v1.z*v1.z+v1.w*v1.w;
  #pragma unroll
  for (int o=32;o;o>>=1){ s += __shfl_xor(s,o); ss += __shfl_xor(ss,o); }
  const float mean = s*(1.f/D_);
  const float rstd = rsqrtf(ss*(1.f/D_) - mean*mean + 1e-5f);
  float4 g0 = *(const float4*)(g + lane*4);
  float4 g1 = *(const float4*)(g + 256 + lane*4);
  float4 b0 = *(const float4*)(b + lane*4);
  float4 b1 = *(const float4*)(b + 256 + lane*4);
  float4 o0, o1;
  o0.x=(v0.x-mean)*rstd*g0.x+b0.x; o0.y=(v0.y-mean)*rstd*g0.y+b0.y;
  o0.z=(v0.z-mean)*rstd*g0.z+b0.z; o0.w=(v0.w-mean)*rstd*g0.w+b0.w;
  o1.x=(v1.x-mean)*rstd*g1.x+b1.x; o1.y=(v1.y-mean)*rstd*g1.y+b1.y;
  o1.z=(v1.z-mean)*rstd*g1.z+b1.z; o1.w=(v1.w-mean)*rstd*g1.w+b1.w;
  bf16* yr = y + row*D_;
  st_bf4(yr + lane*4, o0);
  st_bf4(yr + 256 + lane*4, o1);
}

// ---------------- kmax init ------------------------------------------------
__global__ void kinit_k(unsigned* __restrict__ kmax, int n){
  int i = blockIdx.x*256 + threadIdx.x;
  if (i < n) kmax[i] = 0u;
}

// ---------------- feature-map epilogue -------------------------------------
// qk f32 [RC][512] (raw q or k), dd f32 [RC][512] -> fp [NBH][S][64]
// QUERY=1: fp = 0.125*(exp(dd - diag - rowmax)+1e-4)
// QUERY=0: fp = dd - diag; atomicMax(kmax[bh], rowmax(dd))
template<int QUERY>
__global__ __launch_bounds__(256)
void feat2_k(const float* __restrict__ qk, const float* __restrict__ dd,
             float* __restrict__ fp, unsigned* __restrict__ kmax, int total)
{
  const int idx = blockIdx.x*4 + (threadIdx.x>>6);
  if (idx >= total) return;
  const int lane = threadIdx.x&63;
  const int r = idx>>3, h = idx&7;
  float qv = qk[(size_t)r*512 + h*64 + lane]*NORM_;
  float sq = qv*qv;
  #pragma unroll
  for (int o=32;o;o>>=1) sq += __shfl_xor(sq,o);
  const float diag = 0.5f*sq;
  float dv = dd[(size_t)r*512 + h*64 + lane];
  float mx = dv;
  #pragma unroll
  for (int o=32;o;o>>=1) mx = fmaxf(mx, __shfl_xor(mx,o));
  const int b_l = r/S_, s = r - b_l*S_;
  const size_t orow = ((size_t)(b_l*8+h)*S_ + s)*64 + lane;
  if (QUERY){
    fp[orow] = 0.125f*(expf(dv - diag - mx) + 1e-4f);
  } else {
    fp[orow] = dv - diag;
    if (lane==0) atomicMax(&kmax[b_l*8+h], flipf(mx));
  }
}

// ---------------- kp finalize: exp with global stab, plus kps = sum_s kp ---
__global__ __launch_bounds__(256)
void kpfin_k(float* __restrict__ kp, const unsigned* __restrict__ kmax,
             float* __restrict__ kps)
{
  __shared__ float red[256][4];
  const int bh = blockIdx.x, tid = threadIdx.x;
  const float stab = unflipf(kmax[bh]);
  float* base = kp + (size_t)bh*S_*64;
  float p0=0,p1=0,p2=0,p3=0;
  for (int i=tid; i < S_*16; i += 256){
    float4 vv = *(float4*)(base + (size_t)i*4);
    vv.x = 0.125f*(expf(vv.x - stab)+1e-4f);
    vv.y = 0.125f*(expf(vv.y - stab)+1e-4f);
    vv.z = 0.125f*(expf(vv.z - stab)+1e-4f);
    vv.w = 0.125f*(expf(vv.w - stab)+1e-4f);
    *(float4*)(base + (size_t)i*4) = vv;
    p0+=vv.x; p1+=vv.y; p2+=vv.z; p3+=vv.w;
  }
  red[tid][0]=p0; red[tid][1]=p1; red[tid][2]=p2; red[tid][3]=p3;
  __syncthreads();
  if (tid < 64){
    const int g = tid>>2, c = tid&3;
    float s = 0.f;
    #pragma unroll
    for (int j=0;j<16;j++) s += red[g + j*16][c];
    kps[bh*64 + tid] = s;
  }
}

// ---------------- ctx[bh,m,d] = sum_s kp[bh,s,m]*v[b,s,h,d] ---------------
__global__ __launch_bounds__(256)
void ctx_k(const float* __restrict__ kp, const float* __restrict__ v,
           float* __restrict__ ctx)
{
  __shared__ float kc[32][64], vc[32][64];
  const int bh = blockIdx.x, tid = threadIdx.x;
  const int b = bh>>3, h = bh&7;
  const float* kpb = kp + (size_t)bh*S_*64;
  const int mq = tid>>4, dq = tid&15;
  float acc[4][4];
  #pragma unroll
  for (int i=0;i<4;i++)
    #pragma unroll
    for (int j=0;j<4;j++) acc[i][j]=0.f;
  for (int s0=0; s0<S_; s0+=32){
    for (int i=tid; i<512; i+=256){
      const int rr = i>>4, cc = (i&15)*4;
      *(float4*)&kc[rr][cc] = *(const float4*)(kpb + (size_t)(s0+rr)*64 + cc);
      *(float4*)&vc[rr][cc] = *(const float4*)(v + ((size_t)(b*S_+s0+rr)*H_ + h)*64 + cc);
    }
    __syncthreads();
    #pragma unroll 8
    for (int ssi=0; ssi<32; ++ssi){
      float a0=kc[ssi][mq*4+0],a1=kc[ssi][mq*4+1],a2=kc[ssi][mq*4+2],a3=kc[ssi][mq*4+3];
      float b0=vc[ssi][dq*4+0],b1=vc[ssi][dq*4+1],b2=vc[ssi][dq*4+2],b3=vc[ssi][dq*4+3];
      acc[0][0]+=a0*b0; acc[0][1]+=a0*b1; acc[0][2]+=a0*b2; acc[0][3]+=a0*b3;
      acc[1][0]+=a1*b0; acc[1][1]+=a1*b1; acc[1][2]+=a1*b2; acc[1][3]+=a1*b3;
      acc[2][0]+=a2*b0; acc[2][1]+=a2*b1; acc[2][2]+=a2*b2; acc[2][3]+=a2*b3;
      acc[3][0]+=a3*b0; acc[3][1]+=a3*b1; acc[3][2]+=a3*b2; acc[3][3]+=a3*b3;
    }
    __syncthreads();
  }
  #pragma unroll
  for (int i=0;i<4;i++)
    #pragma unroll
    for (int j=0;j<4;j++)
      ctx[((size_t)bh*64 + mq*4+i)*64 + dq*4+j] = acc[i][j];
}

// ---------------- out[b,s,h,d] = (qp[bh,s,:]@ctx[bh,:,d]) / den, bf16 out --
__global__ __launch_bounds__(256)
void attnout_k(const float* __restrict__ qp, const float* __restrict__ ctx,
               const float* __restrict__ kps, bf16* __restrict__ out)
{
  __shared__ float cl[4096];
  __shared__ float kl[64];
  __shared__ float qL[4][64];
  const int bh = blockIdx.x, tid = threadIdx.x;
  for (int i=tid;i<4096;i+=256) cl[i] = ctx[(size_t)bh*4096 + i];
  if (tid<64) kl[tid] = kps[bh*64+tid];
  const int b = bh>>3, h = bh&7;
  const int d = tid&63, sg = tid>>6;
  const int send = min((int)(blockIdx.y*64+64), S_);
  for (int s0 = blockIdx.y*64; s0 < send; s0 += 4){
    const int sr = s0 + sg;
    __syncthreads();
    qL[sg][d] = qp[((size_t)bh*S_ + sr)*64 + d];
    __syncthreads();
    float a0=0,a1=0,a2=0,a3=0, e0=0,e1=0,e2=0,e3=0;
    #pragma unroll
    for (int m=0;m<64;m+=4){
      float q0=qL[sg][m], q1=qL[sg][m+1], q2=qL[sg][m+2], q3=qL[sg][m+3];
      a0 += q0*cl[(m  )*64+d]; a1 += q1*cl[(m+1)*64+d];
      a2 += q2*cl[(m+2)*64+d]; a3 += q3*cl[(m+3)*64+d];
      e0 += q0*kl[m]; e1 += q1*kl[m+1]; e2 += q2*kl[m+2]; e3 += q3*kl[m+3];
    }
    const float den = (e0+e1)+(e2+e3);
    const float o = ((a0+a1)+(a2+a3))/den;
    out[((size_t)(b*S_+sr)*H_ + h)*64 + d] = __float2bfloat16(o);
  }
}

// ---------------- head: out[b,c] = (mean_s h[b,s,:]) @ fc_w + fc_b ---------
__global__ __launch_bounds__(256)
void head_k(const float* __restrict__ h, const float* __restrict__ fcw,
            const float* __restrict__ fcb, float* __restrict__ out)
{
  __shared__ float red[256][2];
  const int b = blockIdx.x, tid = threadIdx.x;
  const float* hb = h + (size_t)b*S_*D_;
  float s0=0.f, s1=0.f;
  for (int s=0; s<S_; ++s){
    s0 += hb[(size_t)s*D_ + tid];
    s1 += hb[(size_t)s*D_ + tid + 256];
  }
  const float m0 = s0*(1.f/S_), m1 = s1*(1.f/S_);
  red[tid][0] = m0*fcw[tid*2+0] + m1*fcw[(tid+256)*2+0];
  red[tid][1] = m0*fcw[tid*2+1] + m1*fcw[(tid+256)*2+1];
  __syncthreads();
  for (int st=128; st; st>>=1){
    if (tid<st){ red[tid][0]+=red[tid+st][0]; red[tid][1]+=red[tid+st][1]; }
    __syncthreads();
  }
  if (tid==0){ out[b*2+0]=red[0][0]+fcb[0]; out[b*2+1]=red[0][1]+fcb[1]; }
}

extern "C" void kernel_launch(void* const* d_in, const int* in_sizes, int n_in,
                              void* d_out, int out_size, void* d_ws, size_t ws_size,
                              hipStream_t stream)
{
  const float* x     = (const float*)d_in[0];
  const float* emb_w = (const float*)d_in[1];
  const float* emb_b = (const float*)d_in[2];
  const float* pos   = (const float*)d_in[3];
  const float* ln1_g = (const float*)d_in[4];
  const float* ln1_b = (const float*)d_in[5];
  const float* wq    = (const float*)d_in[6];
  const float* bq    = (const float*)d_in[7];
  const float* wk    = (const float*)d_in[8];
  const float* bk    = (const float*)d_in[9];
  const float* wv    = (const float*)d_in[10];
  const float* bv    = (const float*)d_in[11];
  const float* wo    = (const float*)d_in[12];
  const float* bo    = (const float*)d_in[13];
  const float* proj  = (const float*)d_in[14];
  const float* ln2_g = (const float*)d_in[15];
  const float* ln2_b = (const float*)d_in[16];
  const float* w1    = (const float*)d_in[17];
  const float* b1    = (const float*)d_in[18];
  const float* w2    = (const float*)d_in[19];
  const float* b2    = (const float*)d_in[20];
  const float* fc_w  = (const float*)d_in[21];
  const float* fc_b  = (const float*)d_in[22];
  float* out = (float*)d_out;

  const size_t W55 = (size_t)512*512, W52 = (size_t)512*2048;

  // ---- fixed (weight) region ----
  char* p = (char*)d_ws;
  auto take = [&](size_t bytes)->char*{
    char* r = p; p += (bytes + 255) & ~(size_t)255; return r;
  };
  bf16* wqT  = (bf16*)take(L_*W55*2);
  bf16* wkT  = (bf16*)take(L_*W55*2);
  bf16* wvT  = (bf16*)take(L_*W55*2);
  bf16* woT  = (bf16*)take(L_*W55*2);
  bf16* w1T  = (bf16*)take(L_*W52*2);
  bf16* w2T  = (bf16*)take(L_*W52*2);
  bf16* wqpT = (bf16*)take(L_*W55*2);
  bf16* wkpT = (bf16*)take(L_*W55*2);
  bf16* embT = (bf16*)take((size_t)64*512*2);
  bf16* xbf  = (bf16*)take((size_t)B_*S_*DIN_*2);
  float* bqp = (float*)take(L_*512*4);
  float* bkp = (float*)take(L_*512*4);
  const size_t fixed_bytes = (size_t)(p - (char*)d_ws);

  // ---- pick largest batch-chunk NB ----
  int NB = 64; size_t need = 0;
  for (;; NB >>= 1){
    size_t RC = (size_t)NB*S_, nbh = (size_t)NB*H_;
    need = fixed_bytes + 5*RC*512*4 + RC*512*2 + nbh*4096*4 + nbh*64*4 + ((nbh*4+255)&~(size_t)255) + 4096;
    if (need <= ws_size || NB == 1) break;
  }
  if (need > ws_size) return;
  const size_t RC = (size_t)NB*S_;
  const int NBH = NB*H_, rows = (int)RC;

  float* hbuf = (float*)take(RC*512*4);
  float* b1f  = (float*)take(RC*512*4);
  float* b2f  = (float*)take(RC*512*4);   // contiguous with b1f (2048B rows)
  float* b3f  = (float*)take(RC*512*4);
  float* b4f  = (float*)take(RC*512*4);
  bf16*  ybf  = (bf16*)take(RC*512*2);
  float* ctx  = (float*)take((size_t)NBH*4096*4);
  float* kps  = (float*)take((size_t)NBH*64*4);
  unsigned* kmax = (unsigned*)take((size_t)NBH*4);
  bf16* hidbf = (bf16*)b1f;               // FFN hidden: spans b1f+b2f

  dim3 blk(256);

  // ---- per-launch weight prep ----
  for (int l=0; l<L_; ++l){
    convT_k<<<dim3(16,16), blk, 0, stream>>>(wq + l*W55, wqT + l*W55, 512, 512);
    convT_k<<<dim3(16,16), blk, 0, stream>>>(wk + l*W55, wkT + l*W55, 512, 512);
    convT_k<<<dim3(16,16), blk, 0, stream>>>(wv + l*W55, wvT + l*W55, 512, 512);
    convT_k<<<dim3(16,16), blk, 0, stream>>>(wo + l*W55, woT + l*W55, 512, 512);
    convT_k<<<dim3(64,16), blk, 0, stream>>>(w1 + l*W52, w1T + l*W52, 512, 2048);
    convT_k<<<dim3(16,64), blk, 0, stream>>>(w2 + l*W52, w2T + l*W52, 2048, 512);
    projw_k<<<dim3(8,8), blk, 0, stream>>>(wq + l*W55, proj + l*4096, wqpT + l*W55);
    projw_k<<<dim3(8,8), blk, 0, stream>>>(wk + l*W55, proj + l*4096, wkpT + l*W55);
    bproj_k<<<2, blk, 0, stream>>>(bq + l*512, proj + l*4096, bqp + l*512);
    bproj_k<<<2, blk, 0, stream>>>(bk + l*512, proj + l*4096, bkp + l*512);
  }
  convT_k<<<dim3(16,2), blk, 0, stream>>>(emb_w, embT, 64, 512);
  conv_k<<<(B_*S_*DIN_/4 + 255)/256, blk, 0, stream>>>(x, xbf, B_*S_*DIN_/4);

  const int rg = (rows + 127)/128;
  const int fg = (rows*8 + 3)/4;

  for (int bc = 0; bc < B_/NB; ++bc){
    const bf16* xc = xbf + (size_t)bc*RC*DIN_;
    float* outc = out + (size_t)bc*NB*2;

    // h = x @ emb_w + emb_b + pos[s]
    gemm_bf<0,1,0><<<dim3(4, rg), blk, 0, stream>>>(
        xc, embT, emb_b, pos, hbuf, nullptr, rows, 512, 64, S_);

    for (int l=0; l<L_; ++l){
      // y = LN(h) -> bf16
      ln_k<<<rows/4, blk, 0, stream>>>(hbuf, ln1_g + l*512, ln1_b + l*512, ybf);
      // q, ddq -> qp (b3f)
      gemm_bf<0,0,0><<<dim3(4, rg), blk, 0, stream>>>(ybf, wqT + l*W55, bq + l*512, nullptr, b1f, nullptr, rows, 512, 512, 0);
      gemm_bf<0,0,0><<<dim3(4, rg), blk, 0, stream>>>(ybf, wqpT + l*W55, bqp + l*512, nullptr, b2f, nullptr, rows, 512, 512, 0);
      feat2_k<1><<<fg, blk, 0, stream>>>(b1f, b2f, b3f, nullptr, rows*8);
      // k, ddk -> kp (b4f) + kmax
      gemm_bf<0,0,0><<<dim3(4, rg), blk, 0, stream>>>(ybf, wkT + l*W55, bk + l*512, nullptr, b1f, nullptr, rows, 512, 512, 0);
      gemm_bf<0,0,0><<<dim3(4, rg), blk, 0, stream>>>(ybf, wkpT + l*W55, bkp + l*512, nullptr, b2f, nullptr, rows, 512, 512, 0);
      kinit_k<<<(NBH+255)/256, blk, 0, stream>>>(kmax, NBH);
      feat2_k<0><<<fg, blk, 0, stream>>>(b1f, b2f, b4f, kmax, rows*8);
      kpfin_k<<<NBH, blk, 0, stream>>>(b4f, kmax, kps);
      // v
      gemm_bf<0,0,0><<<dim3(4, rg), blk, 0, stream>>>(ybf, wvT + l*W55, bv + l*512, nullptr, b1f, nullptr, rows, 512, 512, 0);
      // ctx, attn out (bf16 into ybf)
      ctx_k<<<NBH, blk, 0, stream>>>(b4f, b1f, ctx);
      attnout_k<<<dim3(NBH, (S_+63)/64), blk, 0, stream>>>(b3f, ctx, kps, ybf);
      // h += attnout @ wo + bo
      gemm_bf<0,1,0><<<dim3(4, rg), blk, 0, stream>>>(ybf, woT + l*W55, bo + l*512, hbuf, hbuf, nullptr, rows, 512, 512, 0);
      // FFN: h += gelu(LN2(h)@w1+b1)@w2 + b2
      ln_k<<<rows/4, blk, 0, stream>>>(hbuf, ln2_g + l*512, ln2_b + l*512, ybf);
      gemm_bf<1,0,1><<<dim3(16, rg), blk, 0, stream>>>(ybf, w1T + l*W52, b1 + l*2048, nullptr, nullptr, hidbf, rows, 2048, 512, 0);
      gemm_bf<0,1,0><<<dim3(4, rg), blk, 0, stream>>>(hidbf, w2T + l*W52, b2 + l*512, hbuf, hbuf, nullptr, rows, 512, 2048, 0);
    }
    head_k<<<NB, blk, 0, stream>>>(hbuf, fc_w, fc_b, outc);
  }
}

// Round 4
// 4027.282 us; speedup vs baseline: 3.8798x; 1.9871x over previous
//
#include <hip/hip_runtime.h>
#include <hip/hip_bf16.h>

#define B_   64
#define S_   800
#define DIN_ 64
#define D_   512
#define H_   8
#define DH_  64
#define M_   64
#define L_   2
#define FF_  2048

typedef __hip_bfloat16 bf16;
typedef __attribute__((ext_vector_type(8))) short bf16x8;
typedef __attribute__((ext_vector_type(4))) float f32x4;

#define NORM_ 0.35355339059327373f   // 64^(-1/4)

__device__ __forceinline__ float gelu_f(float x){
  float x3 = x*x*x;
  return 0.5f*x*(1.f + tanhf(0.7978845608028654f*(x + 0.044715f*x3)));
}
__device__ __forceinline__ void st_bf4(bf16* p, float4 v){
  union { bf16 b[4]; unsigned long long u; } q;
  q.b[0]=__float2bfloat16(v.x); q.b[1]=__float2bfloat16(v.y);
  q.b[2]=__float2bfloat16(v.z); q.b[3]=__float2bfloat16(v.w);
  *(unsigned long long*)p = q.u;
}
__device__ __forceinline__ void gld16(const void* g, void* l){
  __builtin_amdgcn_global_load_lds((const __attribute__((address_space(1))) void*)g,
                                   (__attribute__((address_space(3))) void*)l, 16, 0, 0);
}

// ---------------- shared MFMA tile core (m97 structure) --------------------
// A bf16 [rows][K], Wt bf16 [N][K]. 128x128 tile, BK=32, 256 thr = 4 waves.
// LDS linear [128][32] bf16, staged via global_load_lds width=16.
__device__ __forceinline__ void gemm_tile(const bf16* __restrict__ A,
                                          const bf16* __restrict__ Wt,
                                          int rows, int K, f32x4 (&acc)[4][4])
{
  __shared__ bf16 As[128*32];
  __shared__ bf16 Bs[128*32];
  const int tid = threadIdx.x, wave = tid>>6, lane = tid&63;
  const int row0 = blockIdx.y*128, col0 = blockIdx.x*128;
  const int wm = (wave>>1)*64, wn = (wave&1)*64;
  const int lr = lane&15, lk = (lane>>4)*8;
  const int c0 = wave*2, c1 = c0+1;
  const int sub = lane>>2, kq = (lane&3)*8;   // lane -> (row-in-chunk, k-offset)
  const int ra0 = min(row0 + c0*16 + sub, rows-1);
  const int ra1 = min(row0 + c1*16 + sub, rows-1);
  const bf16* gA0 = A + (size_t)ra0*K + kq;
  const bf16* gA1 = A + (size_t)ra1*K + kq;
  const bf16* gB0 = Wt + (size_t)(col0 + c0*16 + sub)*K + kq;
  const bf16* gB1 = Wt + (size_t)(col0 + c1*16 + sub)*K + kq;
  bf16* lA0 = &As[c0*512]; bf16* lA1 = &As[c1*512];
  bf16* lB0 = &Bs[c0*512]; bf16* lB1 = &Bs[c1*512];
  for (int k0=0; k0<K; k0+=32){
    __syncthreads();                       // prev tile fully consumed
    gld16(gA0 + k0, lA0);  gld16(gA1 + k0, lA1);
    gld16(gB0 + k0, lB0);  gld16(gB1 + k0, lB1);
    __syncthreads();                       // drains vmcnt -> LDS valid
    bf16x8 af[4], bv[4];
    #pragma unroll
    for (int mi=0;mi<4;mi++) af[mi] = *(const bf16x8*)&As[(wm+mi*16+lr)*32 + lk];
    #pragma unroll
    for (int ni=0;ni<4;ni++) bv[ni] = *(const bf16x8*)&Bs[(wn+ni*16+lr)*32 + lk];
    #pragma unroll
    for (int mi=0;mi<4;mi++)
      #pragma unroll
      for (int ni=0;ni<4;ni++)
        acc[mi][ni] = __builtin_amdgcn_mfma_f32_16x16x32_bf16(af[mi], bv[ni], acc[mi][ni], 0,0,0);
  }
}

// ---------------- standard GEMM: C = act(A@W + bias) (+res) ----------------
template<int ACT, int RES, int OUTB>
__global__ __launch_bounds__(256)
void gemm2_k(const bf16* __restrict__ A, const bf16* __restrict__ Wt,
             const float* __restrict__ bias, const float* __restrict__ res,
             float* __restrict__ Cf, bf16* __restrict__ Cb,
             int rows, int N, int K, int res_mod)
{
  f32x4 acc[4][4];
  #pragma unroll
  for (int i=0;i<4;i++)
    #pragma unroll
    for (int j=0;j<4;j++) acc[i][j] = (f32x4){0.f,0.f,0.f,0.f};
  gemm_tile(A, Wt, rows, K, acc);
  const int tid=threadIdx.x, wave=tid>>6, lane=tid&63;
  const int wm=(wave>>1)*64, wn=(wave&1)*64, lr=lane&15, hi=lane>>4;
  const int row0=blockIdx.y*128, col0=blockIdx.x*128;
  #pragma unroll
  for (int mi=0;mi<4;mi++){
    #pragma unroll
    for (int i=0;i<4;i++){
      const int r = row0 + wm + mi*16 + hi*4 + i;
      if (r >= rows) continue;
      #pragma unroll
      for (int ni=0;ni<4;ni++){
        const int c = col0 + wn + ni*16 + lr;
        float v = acc[mi][ni][i] + bias[c];
        if (ACT) v = gelu_f(v);
        if (RES) v += res[(size_t)(res_mod ? (r % res_mod) : r)*N + c];
        if (OUTB) Cb[(size_t)r*N + c] = __float2bfloat16(v);
        else      Cf[(size_t)r*N + c] = v;
      }
    }
  }
}

// ---------------- mega GEMM: N=2560 sections [q|ddq|k|ddk|v] ---------------
// sec 0 (q): store diag_q[r][h] only; sec 2 (k): diag_k.
// sec 1 -> ddq, sec 3 -> ddk, sec 4 -> v (all fp32 [rows][512]).
__global__ __launch_bounds__(256)
void gemm_mega_k(const bf16* __restrict__ A, const bf16* __restrict__ Wcat,
                 const float* __restrict__ bcat, int rows,
                 float* __restrict__ ddq, float* __restrict__ ddk,
                 float* __restrict__ vb, float* __restrict__ dq,
                 float* __restrict__ dk)
{
  f32x4 acc[4][4];
  #pragma unroll
  for (int i=0;i<4;i++)
    #pragma unroll
    for (int j=0;j<4;j++) acc[i][j] = (f32x4){0.f,0.f,0.f,0.f};
  gemm_tile(A, Wcat, rows, 512, acc);
  const int tid=threadIdx.x, wave=tid>>6, lane=tid&63;
  const int wm=(wave>>1)*64, wn=(wave&1)*64, lr=lane&15, hi=lane>>4;
  const int row0 = blockIdx.y*128;
  const int gbase = blockIdx.x*128 + wn;     // 64-aligned, one section
  const int sec = gbase>>9;
  if (sec==0 || sec==2){
    float* dst = (sec==0)? dq : dk;
    const int h = (gbase>>6)&7;
    #pragma unroll
    for (int mi=0;mi<4;mi++){
      #pragma unroll
      for (int i=0;i<4;i++){
        const int r = row0 + wm + mi*16 + hi*4 + i;
        float s = 0.f;
        #pragma unroll
        for (int ni=0;ni<4;ni++){
          float v = (acc[mi][ni][i] + bcat[gbase + ni*16 + lr]) * NORM_;
          s += v*v;
        }
        s += __shfl_xor(s,1); s += __shfl_xor(s,2);
        s += __shfl_xor(s,4); s += __shfl_xor(s,8);
        if (lr==0 && r<rows) dst[(size_t)r*8 + h] = 0.5f*s;
      }
    }
  } else {
    float* dst = (sec==1)? ddq : (sec==3)? ddk : vb;
    const int cb = (sec==1)? 512 : (sec==3)? 1536 : 2048;
    #pragma unroll
    for (int mi=0;mi<4;mi++){
      #pragma unroll
      for (int i=0;i<4;i++){
        const int r = row0 + wm + mi*16 + hi*4 + i;
        if (r >= rows) continue;
        #pragma unroll
        for (int ni=0;ni<4;ni++){
          const int c = gbase + ni*16 + lr;
          dst[(size_t)r*512 + (c - cb)] = acc[mi][ni][i] + bcat[c];
        }
      }
    }
  }
}

// ---------------- weight transpose+convert: f32 [K][N] -> bf16 [N][K] ------
__global__ __launch_bounds__(256)
void convT_k(const float* __restrict__ src, bf16* __restrict__ dst, int K, int N)
{
  __shared__ float t[32][33];
  const int n0 = blockIdx.x*32, k0 = blockIdx.y*32;
  const int j = threadIdx.x&31, i0 = threadIdx.x>>5;
  #pragma unroll
  for (int i=i0; i<32; i+=8) t[i][j] = src[(size_t)(k0+i)*N + n0 + j];
  __syncthreads();
  #pragma unroll
  for (int i=i0; i<32; i+=8) dst[(size_t)(n0+i)*K + k0 + j] = __float2bfloat16(t[j][i]);
}

__global__ void conv_k(const float* __restrict__ src, bf16* __restrict__ dst, int n4)
{
  int i = blockIdx.x*256 + threadIdx.x;
  if (i < n4){ float4 v = ((const float4*)src)[i]; st_bf4(dst + (size_t)i*4, v); }
}

__global__ void copyf_k(const float* __restrict__ s, float* __restrict__ d, int n){
  int i = blockIdx.x*256 + threadIdx.x;
  if (i < n) d[i] = s[i];
}

// folded feature weight: WpT[h*64+m][c] = norm*sum_d w[c,h*64+d]*proj[m,d]
__global__ __launch_bounds__(256)
void projw_k(const float* __restrict__ w, const float* __restrict__ proj,
             bf16* __restrict__ wpT)
{
  __shared__ float pj[64][64];
  __shared__ float wsh[64][65];
  const int h = blockIdx.x, c0 = blockIdx.y*64;
  const int tid = threadIdx.x, lane = tid&63, tg = tid>>6;
  for (int i=tid; i<4096; i+=256) pj[i>>6][i&63] = proj[i];
  for (int i=tg; i<64; i+=4) wsh[i][lane] = w[(size_t)(c0+i)*512 + h*64 + lane];
  __syncthreads();
  float acc[16];
  #pragma unroll
  for (int j=0;j<16;j++) acc[j]=0.f;
  for (int d=0; d<64; ++d){
    float wv = wsh[lane][d];
    #pragma unroll
    for (int j=0;j<16;j++) acc[j] += wv * pj[tg*16+j][d];
  }
  #pragma unroll
  for (int j=0;j<16;j++)
    wpT[(size_t)(h*64 + tg*16 + j)*512 + c0 + lane] = __float2bfloat16(acc[j]*NORM_);
}

// folded feature bias: bp[h*64+m] = norm*sum_d b[h*64+d]*proj[m,d]
__global__ void bproj_k(const float* __restrict__ b, const float* __restrict__ proj,
                        float* __restrict__ bp)
{
  int hm = blockIdx.x*256 + threadIdx.x;
  if (hm >= 512) return;
  int h = hm>>6, m = hm&63;
  float acc = 0.f;
  for (int d=0; d<64; ++d) acc += b[h*64+d]*proj[m*64+d];
  bp[hm] = acc*NORM_;
}

// ---------------- LayerNorm (grid-stride, bf16 out) ------------------------
__global__ __launch_bounds__(256)
void ln_k(const float* __restrict__ x, const float* __restrict__ g,
          const float* __restrict__ b, bf16* __restrict__ y, int nrows)
{
  const int wid = threadIdx.x>>6, lane = threadIdx.x&63;
  float4 g0 = *(const float4*)(g + lane*4);
  float4 g1 = *(const float4*)(g + 256 + lane*4);
  float4 b0 = *(const float4*)(b + lane*4);
  float4 b1 = *(const float4*)(b + 256 + lane*4);
  for (size_t row = (size_t)blockIdx.x*4 + wid; row < (size_t)nrows; row += (size_t)gridDim.x*4){
    const float* xr = x + row*D_;
    float4 v0 = *(const float4*)(xr + lane*4);
    float4 v1 = *(const float4*)(xr + 256 + lane*4);
    float s  = v0.x+v0.y+v0.z+v0.w + v1.x+v1.y+v1.z+v1.w;
    float ss = v0.x*v0.x+v0.y*v0.y+v0.z*v0.z+v0.w*v0.w
             + v1.x*v1.x+v1.y*v1.y+v1.z*v1.z+v1.w*v1.w;
    #pragma unroll
    for (int o=32;o;o>>=1){ s += __shfl_xor(s,o); ss += __shfl_xor(ss,o); }
    const float mean = s*(1.f/D_);
    const float rstd = rsqrtf(ss*(1.f/D_) - mean*mean + 1e-5f);
    float4 o0, o1;
    o0.x=(v0.x-mean)*rstd*g0.x+b0.x; o0.y=(v0.y-mean)*rstd*g0.y+b0.y;
    o0.z=(v0.z-mean)*rstd*g0.z+b0.z; o0.w=(v0.w-mean)*rstd*g0.w+b0.w;
    o1.x=(v1.x-mean)*rstd*g1.x+b1.x; o1.y=(v1.y-mean)*rstd*g1.y+b1.y;
    o1.z=(v1.z-mean)*rstd*g1.z+b1.z; o1.w=(v1.w-mean)*rstd*g1.w+b1.w;
    bf16* yr = y + row*D_;
    st_bf4(yr + lane*4, o0);
    st_bf4(yr + 256 + lane*4, o1);
  }
}

// ---------------- kmax[bh] = max over (s,m) of ddk -------------------------
__global__ __launch_bounds__(256)
void kmax_k(const float* __restrict__ ddk, float* __restrict__ kmax)
{
  const int bh = blockIdx.x, tid = threadIdx.x;
  const int b = bh>>3, h = bh&7;
  const int j = tid>>4, m4 = (tid&15)*4;
  float mx = -3.4e38f;
  for (int s0=0; s0<S_; s0+=16){
    float4 v = *(const float4*)(ddk + (size_t)(b*S_+s0+j)*512 + h*64 + m4);
    mx = fmaxf(mx, fmaxf(fmaxf(v.x,v.y), fmaxf(v.z,v.w)));
  }
  #pragma unroll
  for (int o=32;o;o>>=1) mx = fmaxf(mx, __shfl_xor(mx,o));
  __shared__ float red[4];
  if ((tid&63)==0) red[tid>>6] = mx;
  __syncthreads();
  if (tid==0) kmax[bh] = fmaxf(fmaxf(red[0],red[1]), fmaxf(red[2],red[3]));
}

// ---------------- featQ: qp = 0.125*(exp(dd - diag - rowmax)+eps) ----------
// 4 rows per wave, float4/lane; dst layout [bh][s][64].
__global__ __launch_bounds__(256)
void featq_k(const float* __restrict__ dd, const float* __restrict__ diag,
             float* __restrict__ qp, int total)
{
  const int wid = threadIdx.x>>6, lane = threadIdx.x&63;
  const int j = lane>>4, m4 = (lane&15)*4;
  for (int t = blockIdx.x*4 + wid; t < total; t += gridDim.x*4){
    const int r = (t>>3)*4 + j, h = t&7;
    float4 v = *(const float4*)(dd + (size_t)r*512 + h*64 + m4);
    const float dg = diag[(size_t)r*8 + h];
    float mx = fmaxf(fmaxf(v.x,v.y), fmaxf(v.z,v.w));
    mx = fmaxf(mx, __shfl_xor(mx,1)); mx = fmaxf(mx, __shfl_xor(mx,2));
    mx = fmaxf(mx, __shfl_xor(mx,4)); mx = fmaxf(mx, __shfl_xor(mx,8));
    float4 o;
    o.x = 0.125f*(expf(v.x - dg - mx)+1e-4f);
    o.y = 0.125f*(expf(v.y - dg - mx)+1e-4f);
    o.z = 0.125f*(expf(v.z - dg - mx)+1e-4f);
    o.w = 0.125f*(expf(v.w - dg - mx)+1e-4f);
    const int b = r/S_, s = r - b*S_;
    *(float4*)(qp + ((size_t)(b*8+h)*S_ + s)*64 + m4) = o;
  }
}

// ---------------- featK: kp = 0.125*(exp(dd - diag - kmax[bh])+eps) --------
__global__ __launch_bounds__(256)
void featk_k(const float* __restrict__ dd, const float* __restrict__ diag,
             const float* __restrict__ kmax, float* __restrict__ kp, int total)
{
  const int wid = threadIdx.x>>6, lane = threadIdx.x&63;
  const int j = lane>>4, m4 = (lane&15)*4;
  for (int t = blockIdx.x*4 + wid; t < total; t += gridDim.x*4){
    const int r = (t>>3)*4 + j, h = t&7;
    float4 v = *(const float4*)(dd + (size_t)r*512 + h*64 + m4);
    const float dg = diag[(size_t)r*8 + h];
    const int b = r/S_, s = r - b*S_;
    const float stab = kmax[b*8+h];
    float4 o;
    o.x = 0.125f*(expf(v.x - dg - stab)+1e-4f);
    o.y = 0.125f*(expf(v.y - dg - stab)+1e-4f);
    o.z = 0.125f*(expf(v.z - dg - stab)+1e-4f);
    o.w = 0.125f*(expf(v.w - dg - stab)+1e-4f);
    *(float4*)(kp + ((size_t)(b*8+h)*S_ + s)*64 + m4) = o;
  }
}

// ---------------- kps[bh][m] = sum_s kp[bh][s][m] (read-only) --------------
__global__ __launch_bounds__(256)
void kpfin_k(const float* __restrict__ kp, float* __restrict__ kps)
{
  const int bh = blockIdx.x, tid = threadIdx.x;
  const int sg = tid>>6, m = tid&63;
  const float* base = kp + (size_t)bh*S_*64;
  float s = 0.f;
  for (int ss=sg; ss<S_; ss+=4) s += base[(size_t)ss*64 + m];
  __shared__ float red[4][64];
  red[sg][m] = s;
  __syncthreads();
  if (tid < 64) kps[bh*64+tid] = red[0][tid]+red[1][tid]+red[2][tid]+red[3][tid];
}

// ---------------- ctx[bh,m,d] = sum_s kp[bh,s,m]*v[b,s,h,d] ---------------
__global__ __launch_bounds__(256)
void ctx_k(const float* __restrict__ kp, const float* __restrict__ v,
           float* __restrict__ ctx)
{
  __shared__ float kc[32][64], vc[32][64];
  const int bh = blockIdx.x, tid = threadIdx.x;
  const int b = bh>>3, h = bh&7;
  const float* kpb = kp + (size_t)bh*S_*64;
  const int mq = tid>>4, dq = tid&15;
  float acc[4][4];
  #pragma unroll
  for (int i=0;i<4;i++)
    #pragma unroll
    for (int j=0;j<4;j++) acc[i][j]=0.f;
  for (int s0=0; s0<S_; s0+=32){
    for (int i=tid; i<512; i+=256){
      const int rr = i>>4, cc = (i&15)*4;
      *(float4*)&kc[rr][cc] = *(const float4*)(kpb + (size_t)(s0+rr)*64 + cc);
      *(float4*)&vc[rr][cc] = *(const float4*)(v + (size_t)(b*S_+s0+rr)*512 + h*64 + cc);
    }
    __syncthreads();
    #pragma unroll 8
    for (int ssi=0; ssi<32; ++ssi){
      float a0=kc[ssi][mq*4+0],a1=kc[ssi][mq*4+1],a2=kc[ssi][mq*4+2],a3=kc[ssi][mq*4+3];
      float b0=vc[ssi][dq*4+0],b1=vc[ssi][dq*4+1],b2=vc[ssi][dq*4+2],b3=vc[ssi][dq*4+3];
      acc[0][0]+=a0*b0; acc[0][1]+=a0*b1; acc[0][2]+=a0*b2; acc[0][3]+=a0*b3;
      acc[1][0]+=a1*b0; acc[1][1]+=a1*b1; acc[1][2]+=a1*b2; acc[1][3]+=a1*b3;
      acc[2][0]+=a2*b0; acc[2][1]+=a2*b1; acc[2][2]+=a2*b2; acc[2][3]+=a2*b3;
      acc[3][0]+=a3*b0; acc[3][1]+=a3*b1; acc[3][2]+=a3*b2; acc[3][3]+=a3*b3;
    }
    __syncthreads();
  }
  #pragma unroll
  for (int i=0;i<4;i++)
    #pragma unroll
    for (int j=0;j<4;j++)
      ctx[((size_t)bh*64 + mq*4+i)*64 + dq*4+j] = acc[i][j];
}

// ---------------- out[b,s,h,d] = (qp[bh,s,:]@ctx[bh,:,d]) / den, bf16 ------
__global__ __launch_bounds__(256)
void attnout_k(const float* __restrict__ qp, const float* __restrict__ ctx,
               const float* __restrict__ kps, bf16* __restrict__ out)
{
  __shared__ float cl[4096];
  __shared__ float kl[64];
  __shared__ float qL[4][64];
  const int bh = blockIdx.x, tid = threadIdx.x;
  for (int i=tid;i<4096;i+=256) cl[i] = ctx[(size_t)bh*4096 + i];
  if (tid<64) kl[tid] = kps[bh*64+tid];
  const int b = bh>>3, h = bh&7;
  const int d = tid&63, sg = tid>>6;
  const int send = min((int)(blockIdx.y*64+64), S_);
  for (int s0 = blockIdx.y*64; s0 < send; s0 += 4){
    const int sr = s0 + sg;
    __syncthreads();
    qL[sg][d] = qp[((size_t)bh*S_ + sr)*64 + d];
    __syncthreads();
    float a0=0,a1=0,a2=0,a3=0, e0=0,e1=0,e2=0,e3=0;
    #pragma unroll
    for (int m=0;m<64;m+=4){
      float q0=qL[sg][m], q1=qL[sg][m+1], q2=qL[sg][m+2], q3=qL[sg][m+3];
      a0 += q0*cl[(m  )*64+d]; a1 += q1*cl[(m+1)*64+d];
      a2 += q2*cl[(m+2)*64+d]; a3 += q3*cl[(m+3)*64+d];
      e0 += q0*kl[m]; e1 += q1*kl[m+1]; e2 += q2*kl[m+2]; e3 += q3*kl[m+3];
    }
    const float den = (e0+e1)+(e2+e3);
    const float o = ((a0+a1)+(a2+a3))/den;
    out[((size_t)(b*S_+sr)*H_ + h)*64 + d] = __float2bfloat16(o);
  }
}

// ---------------- head ----------------------------------------------------
__global__ __launch_bounds__(256)
void head_k(const float* __restrict__ h, const float* __restrict__ fcw,
            const float* __restrict__ fcb, float* __restrict__ out)
{
  __shared__ float red[256][2];
  const int b = blockIdx.x, tid = threadIdx.x;
  const float* hb = h + (size_t)b*S_*D_;
  float s0=0.f, s1=0.f;
  for (int s=0; s<S_; ++s){
    s0 += hb[(size_t)s*D_ + tid];
    s1 += hb[(size_t)s*D_ + tid + 256];
  }
  const float m0 = s0*(1.f/S_), m1 = s1*(1.f/S_);
  red[tid][0] = m0*fcw[tid*2+0] + m1*fcw[(tid+256)*2+0];
  red[tid][1] = m0*fcw[tid*2+1] + m1*fcw[(tid+256)*2+1];
  __syncthreads();
  for (int st=128; st; st>>=1){
    if (tid<st){ red[tid][0]+=red[tid+st][0]; red[tid][1]+=red[tid+st][1]; }
    __syncthreads();
  }
  if (tid==0){ out[b*2+0]=red[0][0]+fcb[0]; out[b*2+1]=red[0][1]+fcb[1]; }
}

extern "C" void kernel_launch(void* const* d_in, const int* in_sizes, int n_in,
                              void* d_out, int out_size, void* d_ws, size_t ws_size,
                              hipStream_t stream)
{
  const float* x     = (const float*)d_in[0];
  const float* emb_w = (const float*)d_in[1];
  const float* emb_b = (const float*)d_in[2];
  const float* pos   = (const float*)d_in[3];
  const float* ln1_g = (const float*)d_in[4];
  const float* ln1_b = (const float*)d_in[5];
  const float* wq    = (const float*)d_in[6];
  const float* bq    = (const float*)d_in[7];
  const float* wk    = (const float*)d_in[8];
  const float* bk    = (const float*)d_in[9];
  const float* wv    = (const float*)d_in[10];
  const float* bv    = (const float*)d_in[11];
  const float* wo    = (const float*)d_in[12];
  const float* bo    = (const float*)d_in[13];
  const float* proj  = (const float*)d_in[14];
  const float* ln2_g = (const float*)d_in[15];
  const float* ln2_b = (const float*)d_in[16];
  const float* w1    = (const float*)d_in[17];
  const float* b1    = (const float*)d_in[18];
  const float* w2    = (const float*)d_in[19];
  const float* b2    = (const float*)d_in[20];
  const float* fc_w  = (const float*)d_in[21];
  const float* fc_b  = (const float*)d_in[22];
  float* out = (float*)d_out;

  const size_t W55 = (size_t)512*512, W52 = (size_t)512*2048;
  const size_t WCAT = (size_t)2560*512;

  char* p = (char*)d_ws;
  auto take = [&](size_t bytes)->char*{
    char* r = p; p += (bytes + 255) & ~(size_t)255; return r;
  };
  bf16* Wcat = (bf16*)take(L_*WCAT*2);
  bf16* woT  = (bf16*)take(L_*W55*2);
  bf16* w1T  = (bf16*)take(L_*W52*2);
  bf16* w2T  = (bf16*)take(L_*W52*2);
  bf16* embT = (bf16*)take((size_t)64*512*2);
  bf16* xbf  = (bf16*)take((size_t)B_*S_*DIN_*2);
  float* bcat= (float*)take(L_*2560*4);
  const size_t fixed_bytes = (size_t)(p - (char*)d_ws);

  int NB = 64; size_t need = 0;
  for (;; NB >>= 1){
    size_t RC = (size_t)NB*S_, nbh = (size_t)NB*H_;
    need = fixed_bytes + 5*RC*512*4 + RC*512*2 + 2*RC*8*4
         + nbh*4096*4 + nbh*64*4 + nbh*4 + 8192;
    if (need <= ws_size || NB == 1) break;
  }
  if (need > ws_size) return;
  const size_t RC = (size_t)NB*S_;
  const int NBH = NB*H_, rows = (int)RC;

  float* hbuf = (float*)take(RC*512*4);
  float* b1f  = (float*)take(RC*512*4);   // ddq -> kp      (b1f+b2f = ffn hidden)
  float* b2f  = (float*)take(RC*512*4);   // ddk
  float* b3f  = (float*)take(RC*512*4);   // qp
  float* b4f  = (float*)take(RC*512*4);   // v
  bf16*  ybf  = (bf16*)take(RC*512*2);
  float* dqv  = (float*)take(RC*8*4);
  float* dkv  = (float*)take(RC*8*4);
  float* ctx  = (float*)take((size_t)NBH*4096*4);
  float* kps  = (float*)take((size_t)NBH*64*4);
  float* kmaxf= (float*)take((size_t)NBH*4);
  bf16* hidbf = (bf16*)b1f;

  dim3 blk(256);

  // ---- per-launch weight prep ----
  for (int l=0; l<L_; ++l){
    bf16* Wl = Wcat + (size_t)l*WCAT;
    float* bl = bcat + (size_t)l*2560;
    convT_k<<<dim3(16,16), blk, 0, stream>>>(wq + l*W55, Wl,            512, 512);
    projw_k<<<dim3(8,8),   blk, 0, stream>>>(wq + l*W55, proj + l*4096, Wl + 512*512);
    convT_k<<<dim3(16,16), blk, 0, stream>>>(wk + l*W55, Wl + 1024*512, 512, 512);
    projw_k<<<dim3(8,8),   blk, 0, stream>>>(wk + l*W55, proj + l*4096, Wl + 1536*512);
    convT_k<<<dim3(16,16), blk, 0, stream>>>(wv + l*W55, Wl + 2048*512, 512, 512);
    copyf_k<<<2, blk, 0, stream>>>(bq + l*512, bl,        512);
    bproj_k<<<2, blk, 0, stream>>>(bq + l*512, proj + l*4096, bl + 512);
    copyf_k<<<2, blk, 0, stream>>>(bk + l*512, bl + 1024, 512);
    bproj_k<<<2, blk, 0, stream>>>(bk + l*512, proj + l*4096, bl + 1536);
    copyf_k<<<2, blk, 0, stream>>>(bv + l*512, bl + 2048, 512);
    convT_k<<<dim3(16,16), blk, 0, stream>>>(wo + l*W55, woT + l*W55, 512, 512);
    convT_k<<<dim3(64,16), blk, 0, stream>>>(w1 + l*W52, w1T + l*W52, 512, 2048);
    convT_k<<<dim3(16,64), blk, 0, stream>>>(w2 + l*W52, w2T + l*W52, 2048, 512);
  }
  convT_k<<<dim3(16,2), blk, 0, stream>>>(emb_w, embT, 64, 512);
  conv_k<<<(B_*S_*DIN_/4 + 255)/256, blk, 0, stream>>>(x, xbf, B_*S_*DIN_/4);

  const int rg = (rows + 127)/128;

  for (int bc = 0; bc < B_/NB; ++bc){
    const bf16* xc = xbf + (size_t)bc*RC*DIN_;
    float* outc = out + (size_t)bc*NB*2;

    gemm2_k<0,1,0><<<dim3(4, rg), blk, 0, stream>>>(
        xc, embT, emb_b, pos, hbuf, nullptr, rows, 512, 64, S_);

    for (int l=0; l<L_; ++l){
      ln_k<<<2048, blk, 0, stream>>>(hbuf, ln1_g + l*512, ln1_b + l*512, ybf, rows);
      gemm_mega_k<<<dim3(20, rg), blk, 0, stream>>>(
          ybf, Wcat + (size_t)l*WCAT, bcat + (size_t)l*2560, rows,
          b1f, b2f, b4f, dqv, dkv);
      kmax_k<<<NBH, blk, 0, stream>>>(b2f, kmaxf);
      featq_k<<<1024, blk, 0, stream>>>(b1f, dqv, b3f, rows*2);
      featk_k<<<1024, blk, 0, stream>>>(b2f, dkv, kmaxf, b1f, rows*2);
      kpfin_k<<<NBH, blk, 0, stream>>>(b1f, kps);
      ctx_k<<<NBH, blk, 0, stream>>>(b1f, b4f, ctx);
      attnout_k<<<dim3(NBH, (S_+63)/64), blk, 0, stream>>>(b3f, ctx, kps, ybf);
      gemm2_k<0,1,0><<<dim3(4, rg), blk, 0, stream>>>(
          ybf, woT + l*W55, bo + l*512, hbuf, hbuf, nullptr, rows, 512, 512, 0);
      ln_k<<<2048, blk, 0, stream>>>(hbuf, ln2_g + l*512, ln2_b + l*512, ybf, rows);
      gemm2_k<1,0,1><<<dim3(16, rg), blk, 0, stream>>>(
          ybf, w1T + l*W52, b1 + l*2048, nullptr, nullptr, hidbf, rows, 2048, 512, 0);
      gemm2_k<0,1,0><<<dim3(4, rg), blk, 0, stream>>>(
          hidbf, w2T + l*W52, b2 + l*512, hbuf, hbuf, nullptr, rows, 512, 2048, 0);
    }
    head_k<<<NB, blk, 0, stream>>>(hbuf, fc_w, fc_b, outc);
  }
}